// Round 21
// baseline (269.800 us; speedup 1.0000x reference)
//
#include <hip/hip_runtime.h>
#include <hip/hip_bf16.h>

#define Cc 128
#define Hh 4
#define Dd 32
#define DPHI2 64
#define Ll 2
#define Tt 2
#define Rr 2

typedef __hip_bfloat16 bf16;
using short8 = __attribute__((ext_vector_type(8))) short;
using f32x4 = __attribute__((ext_vector_type(4))) float;
using f32x2 = __attribute__((ext_vector_type(2))) float;
typedef _Float16 h2 __attribute__((ext_vector_type(2)));
typedef __fp16 fp16x2 __attribute__((ext_vector_type(2)));

__device__ __forceinline__ unsigned short f2bf(float f) {
  union { float f; unsigned u; } v; v.f = f;
  unsigned r = v.u + 0x7fff + ((v.u >> 16) & 1);
  return (unsigned short)(r >> 16);
}
__device__ __forceinline__ h2 u2h(unsigned u) {
  union { unsigned u; h2 h; } v; v.u = u; return v.h;
}
__device__ __forceinline__ unsigned pkh(float a, float b) {
  union { unsigned u; fp16x2 h; } v;
  v.h = __builtin_amdgcn_cvt_pkrtz(a, b);
  return v.u;
}

// ---- fp8 e4m3 helpers (HW cvt on gfx950; guarded fallbacks) ----
__device__ __forceinline__ float fp8_decode1(unsigned char b) {
  unsigned u = b & 0x7f;
  float nrm = __builtin_bit_cast(float, (u << 20) + 0x3C000000u);
  float sub = (float)u * 0.001953125f;
  float v = (u >= 8) ? nrm : sub;
  return (b & 0x80) ? -v : v;
}
template <bool HI>
__device__ __forceinline__ f32x2 fp8x2f(unsigned w) {
#if __has_builtin(__builtin_amdgcn_cvt_pk_f32_fp8)
  return __builtin_amdgcn_cvt_pk_f32_fp8(w, HI);
#else
  unsigned b = HI ? (w >> 16) : (w & 0xffff);
  f32x2 r;
  r[0] = fp8_decode1((unsigned char)b);
  r[1] = fp8_decode1((unsigned char)(b >> 8));
  return r;
#endif
}
#if !__has_builtin(__builtin_amdgcn_cvt_pk_fp8_f32)
__device__ __forceinline__ unsigned char fp8_encode1(float f) {
  unsigned s = (__builtin_bit_cast(unsigned, f) >> 31) << 7;
  float a = fabsf(f);
  a = fminf(a, 448.f);
  unsigned char out;
  if (a < 0.0009765625f) {
    out = 0;
  } else if (a < 0.015625f) {
    out = (unsigned char)(a * 512.f + 0.5f);
  } else {
    unsigned bits = __builtin_bit_cast(unsigned, a);
    int e = (int)(bits >> 23) - 127;
    unsigned m = (bits >> 20) & 7;
    m += (bits >> 19) & 1;
    unsigned ee = (unsigned)(e + 7);
    if (m == 8) { m = 0; ee += 1; }
    if (ee > 15) { ee = 15; m = 6; }
    out = (unsigned char)((ee << 3) | m);
  }
  return out | (unsigned char)s;
}
#endif
__device__ __forceinline__ unsigned pk_fp8x4(float v0, float v1, float v2, float v3) {
#if __has_builtin(__builtin_amdgcn_cvt_pk_fp8_f32)
  int p = __builtin_amdgcn_cvt_pk_fp8_f32(v0, v1, 0, false);
  p = __builtin_amdgcn_cvt_pk_fp8_f32(v2, v3, p, true);
  return (unsigned)p;
#else
  return (unsigned)fp8_encode1(v0) | ((unsigned)fp8_encode1(v1) << 8) |
         ((unsigned)fp8_encode1(v2) << 16) | ((unsigned)fp8_encode1(v3) << 24);
#endif
}

// ---- DPP quad reduce (xor1, xor2 within each 4-lane quad) ----
__device__ __forceinline__ float dpp_add_xor1(float x) {
  int v = __builtin_amdgcn_update_dpp(0, __builtin_bit_cast(int, x), 0xB1, 0xF, 0xF, true);
  return x + __builtin_bit_cast(float, v);
}
__device__ __forceinline__ float dpp_add_xor2(float x) {
  int v = __builtin_amdgcn_update_dpp(0, __builtin_bit_cast(int, x), 0x4E, 0xF, 0xF, true);
  return x + __builtin_bit_cast(float, v);
}

__device__ __forceinline__ float gelu_tanh(float x) {
  float u = 0.7978845608028654f * (x + 0.044715f * x * x * x);
  float t = 1.f - 2.f / (__expf(2.f * u) + 1.f);  // tanh(u)
  return 0.5f * x * (1.f + t);
}

// async 16B global->LDS (LDS dest = wave-uniform base + lane*16)
__device__ __forceinline__ void gload_lds16(const void* gsrc, void* lds) {
  __builtin_amdgcn_global_load_lds(
      (const __attribute__((address_space(1))) unsigned int*)gsrc,
      (__attribute__((address_space(3))) unsigned int*)lds, 16, 0, 0);
}

// ---------------- histM(32-replica) | prep | init -------------------------------
// blocks [0,HBm): movie-side hist, 8 edges/thread; replica r=(e>>11)&31:
//   eoffm[e] = atomicAdd(&cntM32[r*NM+d], 1)  -> per-address contention ~1.6
// blocks [HBm,HBm+PB): prep; blocks [HBm+PB,...): init xout/Xb (float4)
__global__ __launch_bounds__(256) void prep_init_kernel(
    int NM_, int NU_,
    const int* __restrict__ edst, int E_, int* __restrict__ cntM32,
    int* __restrict__ eoffm,
    const float* __restrict__ kw, const float* __restrict__ kb,
    const float* __restrict__ qw, const float* __restrict__ qb,
    const float* __restrict__ vw, const float* __restrict__ vb,
    const float* __restrict__ a_rel, const float* __restrict__ m_rel,
    const float* __restrict__ p_rel, const float* __restrict__ ow,
    const float* __restrict__ ob,
    unsigned short* __restrict__ WT, float* __restrict__ bQKV,
    unsigned short* __restrict__ OWT, float* __restrict__ bO,
    const float* __restrict__ ue, const float* __restrict__ me,
    const float* __restrict__ phi, const float* __restrict__ mw,
    const float* __restrict__ mb,
    float* __restrict__ xout, unsigned short* __restrict__ Xb,
    int HBm, int PB) {
  int b = blockIdx.x;
  if (b < HBm) {
    int base_e = b * 2048;
#pragma unroll
    for (int j = 0; j < 8; ++j) {
      int e = base_e + j * 256 + (int)threadIdx.x;
      if (e < E_) {
        int rep = (e >> 11) & 31;
        eoffm[e] = atomicAdd(&cntM32[rep * NM_ + edst[e]], 1);
      }
    }
    return;
  }
  b -= HBm;
  if (b < PB) {
    int idx = b * 2 + (threadIdx.x >> 7);  // (g,lt) item, 2048 total
    int g = idx >> 2, lt = idx & 3;
    int l = lt >> 1, t = lt & 1, r = t;
    int k = threadIdx.x & 127;
    const float inv_sqrt_d = 0.17677669529663687f;
    const float QSCALE = 1.4426950408889634f / 256.f;  // log2e / S_k
    float val, bval;
    if (g < 128) {
      val = qw[((size_t)lt * Cc + k) * Cc + g] * QSCALE;
      bval = qb[(size_t)lt * Cc + g] * QSCALE;
    } else if (g < 384) {
      int isV = (g >= 256);
      int n = g - (isV ? 256 : 128);
      int h = n >> 5, e = n & 31;
      const float* W = (isV ? vw : kw) + (size_t)lt * Cc * Cc;
      const float* bb = (isV ? vb : kb) + (size_t)lt * Cc;
      const float* Ah = (isV ? m_rel : a_rel) + (((size_t)l * Rr + r) * Hh + h) * Dd * Dd;
      float s = 0.f, sb = 0.f;
      for (int d = 0; d < Dd; ++d) {
        float ae = Ah[d * Dd + e];
        s += W[(size_t)k * Cc + h * Dd + d] * ae;
        sb += bb[h * Dd + d] * ae;
      }
      float scale = isV ? 256.f : p_rel[((size_t)l * Rr + r) * Hh + h] * inv_sqrt_d * 256.f;
      val = s * scale;
      bval = sb * scale;
    } else {
      int n = g - 384;
      val = ow[((size_t)lt * Cc + k) * Cc + n];
      bval = ob[(size_t)lt * Cc + n];
    }
    if (g < 384) {
      WT[((size_t)lt * 384 + g) * Cc + k] = f2bf(val);
      if (k == 0) bQKV[(size_t)lt * 384 + g] = bval;
    } else {
      OWT[((size_t)lt * Cc + (g - 384)) * Cc + k] = f2bf(val);
      if (k == 0) bO[(size_t)lt * Cc + (g - 384)] = bval;
    }
    return;
  }
  // init: 4 channels per thread
  int i4 = (b - PB) * 256 + threadIdx.x;          // group index (4 ch/group)
  int totalU4 = NU_ * 32;                          // 128/4 groups per row
  float4 s;
  size_t o;
  if (i4 < totalU4) {
    o = (size_t)i4 * 4;
    s = *(const float4*)&ue[o];
  } else {
    int mg = i4 - totalU4;
    if (mg >= NM_ * 32) return;
    int m = mg >> 5, c = (mg & 31) * 4;
    o = (size_t)(NU_ * 32 + mg) * 4;
    s = *(const float4*)&me[(size_t)m * Cc + c];
    float4 bmv = *(const float4*)&mb[c];
    s.x += bmv.x; s.y += bmv.y; s.z += bmv.z; s.w += bmv.w;
    const float* ph = phi + (size_t)m * DPHI2;
#pragma unroll 4
    for (int d = 0; d < DPHI2; ++d) {
      float p = ph[d];
      float4 w4 = *(const float4*)&mw[d * Cc + c];
      s.x += p * w4.x; s.y += p * w4.y; s.z += p * w4.z; s.w += p * w4.w;
    }
  }
  *(float4*)&xout[o] = s;
  uint2 pk;
  pk.x = (unsigned)f2bf(s.x) | ((unsigned)f2bf(s.y) << 16);
  pk.y = (unsigned)f2bf(s.z) | ((unsigned)f2bf(s.w) << 16);
  *(uint2*)&Xb[o] = pk;
}

// ---------------- colscan32: cntM32[r][d] -> per-replica bases + movie totals --
__global__ __launch_bounds__(256) void colscan32_kernel(int* __restrict__ cntM32,
                                                        int* __restrict__ cnt, int NM_) {
  int d = blockIdx.x * 256 + threadIdx.x;
  if (d >= NM_) return;
  int run = 0;
#pragma unroll
  for (int r = 0; r < 32; ++r) {
    int* p = cntM32 + (size_t)r * NM_ + d;
    int t = *p;
    *p = run;
    run += t;
  }
  cnt[d] = run;
}

// 3-phase parallel scan: 1024 elems per block
__global__ __launch_bounds__(256) void scan_p1(const int* __restrict__ cnt, int n,
                                               int* __restrict__ psum) {
  int i0 = blockIdx.x * 1024 + threadIdx.x * 4;
  int s = 0;
#pragma unroll
  for (int j = 0; j < 4; ++j) {
    int i = i0 + j;
    if (i < n) s += cnt[i];
  }
#pragma unroll
  for (int off = 1; off < 64; off <<= 1) s += __shfl_xor(s, off, 64);
  __shared__ int wsum[4];
  if ((threadIdx.x & 63) == 0) wsum[threadIdx.x >> 6] = s;
  __syncthreads();
  if (threadIdx.x == 0) psum[blockIdx.x] = wsum[0] + wsum[1] + wsum[2] + wsum[3];
}
__global__ void scan_p2(int* psum, int nb) {
  if (threadIdx.x == 0 && blockIdx.x == 0) {
    int run = 0;
    for (int i = 0; i < nb; ++i) { int v = psum[i]; psum[i] = run; run += v; }
  }
}
__global__ __launch_bounds__(256) void scan_p3(const int* __restrict__ cnt, int n,
                                               const int* __restrict__ psum,
                                               int* __restrict__ rowptr) {
  __shared__ int sdata[256];
  int i0 = blockIdx.x * 1024 + threadIdx.x * 4;
  int a0 = (i0 + 0 < n) ? cnt[i0 + 0] : 0;
  int a1 = (i0 + 1 < n) ? cnt[i0 + 1] : 0;
  int a2 = (i0 + 2 < n) ? cnt[i0 + 2] : 0;
  int a3 = (i0 + 3 < n) ? cnt[i0 + 3] : 0;
  int s = a0 + a1 + a2 + a3;
  sdata[threadIdx.x] = s;
  __syncthreads();
  for (int off = 1; off < 256; off <<= 1) {
    int t = ((int)threadIdx.x >= off) ? sdata[threadIdx.x - off] : 0;
    __syncthreads();
    sdata[threadIdx.x] += t;
    __syncthreads();
  }
  int run = psum[blockIdx.x] + sdata[threadIdx.x] - s;
  if (i0 + 0 < n) rowptr[i0 + 1] = run + a0;
  if (i0 + 1 < n) rowptr[i0 + 2] = run + a0 + a1;
  if (i0 + 2 < n) rowptr[i0 + 3] = run + a0 + a1 + a2;
  if (i0 + 3 < n) rowptr[i0 + 4] = run + s;
  if (blockIdx.x == 0 && threadIdx.x == 0) rowptr[0] = 0;
}

// ---------------- standalone scatter (atomic-free; movie base via cntM32) ------
__global__ void scatter_kernel(const int* __restrict__ esrc, const int* __restrict__ edst,
                               int E_, const int* __restrict__ rowptr,
                               const int* __restrict__ cntM32,
                               const int* __restrict__ eoffm, const int* __restrict__ eoffu,
                               int* __restrict__ srcAll, int NU_, int NM_) {
  int e = blockIdx.x * 256 + threadIdx.x;
  if (e < E_) {
    int s = esrc[e], d = edst[e];
    int rep = (e >> 11) & 31;
    int mbase = cntM32[(size_t)rep * NM_ + d];
    srcAll[rowptr[d] + mbase + eoffm[e]] = s << 8;
    srcAll[rowptr[NM_ + s] + eoffu[e]] = (NU_ + d) << 8;
  }
}

// ---------------- MFMA GEMM (LDS double-buffered B) + prepended HIST-U blocks --
// MODE 0 blocks [0,HB): user-side hist (8 edges/thread): eoffu[e]=atomicAdd(cntU,1)
// blocks [HB, HB+GB): GEMM (users then movies, 128 rows/block).
// MODE 0: QKV proj -> Qc f16 (256B rows) + KVc fp8 rows (256B, [K8|V8]/octet).
// MODE 1: out proj + skip-mix -> xout (f32) + Xb (bf16)  (HB==0)
template <int NCH, int MODE>
__global__ __launch_bounds__(256, 2) void mfma_gemm(
    int HB, int NBU_, int NU_, int NM_,
    const bf16* __restrict__ Abase,
    const bf16* __restrict__ WTl, const float* __restrict__ biasl,
    char* __restrict__ Qc, char* __restrict__ KVc,
    float* __restrict__ xout, unsigned short* __restrict__ Xb,
    const float* __restrict__ skipl,
    const int* __restrict__ esrc, int E_,
    int* __restrict__ cntU, int* __restrict__ eoffu) {
  __shared__ char Bs[2][16384];
  if (MODE == 0 && (int)blockIdx.x < HB) {  // ---- hist-U blocks ----
    int base_e = (int)blockIdx.x * 2048;
#pragma unroll
    for (int j = 0; j < 8; ++j) {
      int e = base_e + j * 256 + (int)threadIdx.x;
      if (e < E_) eoffu[e] = atomicAdd(&cntU[esrc[e]], 1);
    }
    return;
  }
  int bx = (int)blockIdx.x - ((MODE == 0) ? HB : 0);
  int t, row0, M, base;
  if (bx < NBU_) { t = 0; row0 = bx * 128; M = NU_; base = 0; }
  else { t = 1; row0 = (bx - NBU_) * 128; M = NM_; base = NU_; }
  const char* BT = (const char*)(WTl + (size_t)t * (NCH * 64) * Cc);
  const float* bias = biasl + (size_t)t * (NCH * 64);
  int wid = threadIdx.x >> 6, lane = threadIdx.x & 63;
  int rw = row0 + wid * 32;
  bool wact = rw < M;                    // no early return: barriers below
  int lr = lane & 15, lk8 = (lane >> 4) * 8;

  auto stage = [&](int ch, int buf) {
    const char* src = BT + (size_t)ch * 16384;
#pragma unroll
    for (int j = 0; j < 4; ++j) {
      int u = wid * 4 + j;
      int d = u * 1024 + lane * 16;                 // linear LDS dest byte
      int g = d ^ (((d >> 8) & 7) << 4);            // pre-swizzled global src
      gload_lds16(src + g, &Bs[buf][u * 1024]);
    }
  };

  short8 a[2][4];
#pragma unroll
  for (int mt = 0; mt < 2; ++mt) {
    int r = rw + mt * 16 + lr;
    const bf16* ap = Abase + (size_t)(base + r) * Cc + lk8;
#pragma unroll
    for (int kk = 0; kk < 4; ++kk) {
      short8 v = {};
      if (wact && r < M) v = *(const short8*)(ap + kk * 32);
      a[mt][kk] = v;
    }
  }
  float g = 0.f;
  if (MODE == 1) g = 1.f / (1.f + __expf(-skipl[t]));

  stage(0, 0);
#pragma unroll
  for (int ch = 0; ch < NCH; ++ch) {
    int buf = ch & 1;
    __syncthreads();                 // drains vmcnt -> chunk ch arrived
    if (ch + 1 < NCH) stage(ch + 1, buf ^ 1);
    short8 b[4][4];
#pragma unroll
    for (int nt = 0; nt < 4; ++nt) {
      int r = nt * 16 + lr;
#pragma unroll
      for (int kk = 0; kk < 4; ++kk) {
        int a0 = r * 256 + (lk8 + kk * 32) * 2;
        b[nt][kk] = *(const short8*)(&Bs[buf][a0 ^ ((r & 7) << 4)]);
      }
    }
    f32x4 acc[2][4];
#pragma unroll
    for (int mt = 0; mt < 2; ++mt)
#pragma unroll
      for (int nt = 0; nt < 4; ++nt) acc[mt][nt] = (f32x4){0.f, 0.f, 0.f, 0.f};
#pragma unroll
    for (int kk = 0; kk < 4; ++kk)
#pragma unroll
      for (int mt = 0; mt < 2; ++mt)
#pragma unroll
        for (int nt = 0; nt < 4; ++nt)
          acc[mt][nt] = __builtin_amdgcn_mfma_f32_16x16x32_bf16(
              b[nt][kk], a[mt][kk], acc[mt][nt], 0, 0, 0);  // C^T: lane = 1 row, 4 cols
    if (!wact) continue;
#pragma unroll
    for (int mt = 0; mt < 2; ++mt) {
      int r = rw + mt * 16 + lr;
      if (r >= M) continue;
      size_t grow = (size_t)(base + r);
#pragma unroll
      for (int nt = 0; nt < 4; ++nt) {
        int cb = ch * 64 + nt * 16 + 4 * (lane >> 4);
        float4 b4 = *(const float4*)&bias[cb];
        float v0 = acc[mt][nt][0] + b4.x;
        float v1 = acc[mt][nt][1] + b4.y;
        float v2 = acc[mt][nt][2] + b4.z;
        float v3 = acc[mt][nt][3] + b4.w;
        if (MODE == 0) {
          if (cb < Cc) {
            uint2 pk;
            pk.x = pkh(v0, v1); pk.y = pkh(v2, v3);
            *(uint2*)(Qc + grow * 256 + cb * 2) = pk;
          } else {
            int c = cb - 128;          // 0..255: [0,128)=K, [128,256)=V
            int isv = c >> 7; c &= 127;
            int off = (c >> 3) * 16 + (c & 7) + isv * 8;
            unsigned pk = pk_fp8x4(v0, v1, v2, v3);
            *(unsigned*)(KVc + grow * 256 + off) = pk;
          }
        } else {
          float* xp = xout + grow * Cc + cb;
          float4 old = *(const float4*)xp;
          float n0 = g * v0 + (1.f - g) * old.x;
          float n1 = g * v1 + (1.f - g) * old.y;
          float n2 = g * v2 + (1.f - g) * old.z;
          float n3 = g * v3 + (1.f - g) * old.w;
          *(float4*)xp = make_float4(n0, n1, n2, n3);
          uint2 pk;
          pk.x = (unsigned)f2bf(n0) | ((unsigned)f2bf(n1) << 16);
          pk.y = (unsigned)f2bf(n2) | ((unsigned)f2bf(n3) << 16);
          *(uint2*)(Xb + grow * Cc + cb) = pk;
        }
      }
    }
  }
}

// ---------------- fused softmax+agg: SLOT-PER-DST, 8-edge ILP -------------------
__global__ __launch_bounds__(256) void agg_kernel(
    const int* __restrict__ rowptr, const int* __restrict__ srcAll,
    const char* __restrict__ Qc, const char* __restrict__ KVc,
    unsigned short* __restrict__ AGGb, int NM_, int NU_) {
  int wid = threadIdx.x >> 6, lane = threadIdx.x & 63;
  int sub = lane & 15, eo = lane >> 4;
  int NT_ = NM_ + NU_;
  int W = (blockIdx.x * 4 + wid) * 4 + eo;   // this slot's dst
  bool active = W < NT_;
  int Wc = active ? W : NT_ - 1;
  int beg = rowptr[Wc];
  int end = active ? rowptr[Wc + 1] : beg;
  int dnode = (Wc < NM_) ? (NU_ + Wc) : (Wc - NM_);
  int myoff = sub * 16;
  uint4 qv = *(const uint4*)(Qc + (size_t)dnode * 256 + myoff);
  float qf0, qf1, qf2, qf3, qf4, qf5, qf6, qf7;
  {
    h2 t0 = u2h(qv.x), t1 = u2h(qv.y), t2 = u2h(qv.z), t3 = u2h(qv.w);
    qf0 = (float)t0[0]; qf1 = (float)t0[1];
    qf2 = (float)t1[0]; qf3 = (float)t1[1];
    qf4 = (float)t2[0]; qf5 = (float)t2[1];
    qf6 = (float)t3[0]; qf7 = (float)t3[1];
  }
  float acc0 = 0.f, acc1 = 0.f, acc2 = 0.f, acc3 = 0.f;
  float acc4 = 0.f, acc5 = 0.f, acc6 = 0.f, acc7 = 0.f;
  float denom = 0.f;
  const char* KVp = KVc + myoff;

#define CONSUME(KV, WVALID)                                                       \
  {                                                                               \
    f32x2 k01 = fp8x2f<false>((KV).x), k23 = fp8x2f<true>((KV).x);                \
    f32x2 k45 = fp8x2f<false>((KV).y), k67 = fp8x2f<true>((KV).y);                \
    float pA = qf0 * k01[0] + qf1 * k01[1] + qf2 * k23[0] + qf3 * k23[1];         \
    float pB = qf4 * k45[0] + qf5 * k45[1] + qf6 * k67[0] + qf7 * k67[1];         \
    float p = pA + pB;                                                            \
    p = dpp_add_xor1(p);                                                          \
    p = dpp_add_xor2(p);                                                          \
    float w = (WVALID) ? exp2f(p) : 0.f;                                          \
    denom += w;                                                                   \
    f32x2 v01 = fp8x2f<false>((KV).z), v23 = fp8x2f<true>((KV).z);                \
    f32x2 v45 = fp8x2f<false>((KV).w), v67 = fp8x2f<true>((KV).w);                \
    acc0 += w * v01[0]; acc1 += w * v01[1];                                       \
    acc2 += w * v23[0]; acc3 += w * v23[1];                                       \
    acc4 += w * v45[0]; acc5 += w * v45[1];                                       \
    acc6 += w * v67[0]; acc7 += w * v67[1];                                       \
  }

  int e = beg;
  // main: 8 edges in flight per slot
  for (; e + 8 <= end; e += 8) {
    int so0 = srcAll[e + 0];
    int so1 = srcAll[e + 1];
    int so2 = srcAll[e + 2];
    int so3 = srcAll[e + 3];
    int so4 = srcAll[e + 4];
    int so5 = srcAll[e + 5];
    int so6 = srcAll[e + 6];
    int so7 = srcAll[e + 7];
    uint4 kv0 = *(const uint4*)(KVp + (size_t)(unsigned)so0);
    uint4 kv1 = *(const uint4*)(KVp + (size_t)(unsigned)so1);
    uint4 kv2 = *(const uint4*)(KVp + (size_t)(unsigned)so2);
    uint4 kv3 = *(const uint4*)(KVp + (size_t)(unsigned)so3);
    uint4 kv4 = *(const uint4*)(KVp + (size_t)(unsigned)so4);
    uint4 kv5 = *(const uint4*)(KVp + (size_t)(unsigned)so5);
    uint4 kv6 = *(const uint4*)(KVp + (size_t)(unsigned)so6);
    uint4 kv7 = *(const uint4*)(KVp + (size_t)(unsigned)so7);
    CONSUME(kv0, true)
    CONSUME(kv1, true)
    CONSUME(kv2, true)
    CONSUME(kv3, true)
    CONSUME(kv4, true)
    CONSUME(kv5, true)
    CONSUME(kv6, true)
    CONSUME(kv7, true)
  }
  // tail: 4-at-a-time masked
  for (; __any(e < end); e += 4) {
    bool v0 = e < end, v1 = (e + 1) < end, v2 = (e + 2) < end, v3 = (e + 3) < end;
    int so0 = srcAll[v0 ? e : 0];
    int so1 = srcAll[v1 ? (e + 1) : 0];
    int so2 = srcAll[v2 ? (e + 2) : 0];
    int so3 = srcAll[v3 ? (e + 3) : 0];
    uint4 kv0 = *(const uint4*)(KVp + (size_t)(unsigned)so0);
    uint4 kv1 = *(const uint4*)(KVp + (size_t)(unsigned)so1);
    uint4 kv2 = *(const uint4*)(KVp + (size_t)(unsigned)so2);
    uint4 kv3 = *(const uint4*)(KVp + (size_t)(unsigned)so3);
    CONSUME(kv0, v0)
    CONSUME(kv1, v1)
    CONSUME(kv2, v2)
    CONSUME(kv3, v3)
  }
#undef CONSUME

  if (active) {
    float inv = 1.f / (denom + 1e-16f) * 0.00390625f;  // /256 V scale
    float o0 = gelu_tanh(acc0 * inv);
    float o1 = gelu_tanh(acc1 * inv);
    float o2 = gelu_tanh(acc2 * inv);
    float o3 = gelu_tanh(acc3 * inv);
    float o4 = gelu_tanh(acc4 * inv);
    float o5 = gelu_tanh(acc5 * inv);
    float o6 = gelu_tanh(acc6 * inv);
    float o7 = gelu_tanh(acc7 * inv);
    uint4 pk;
    pk.x = (unsigned)f2bf(o0) | ((unsigned)f2bf(o1) << 16);
    pk.y = (unsigned)f2bf(o2) | ((unsigned)f2bf(o3) << 16);
    pk.z = (unsigned)f2bf(o4) | ((unsigned)f2bf(o5) << 16);
    pk.w = (unsigned)f2bf(o6) | ((unsigned)f2bf(o7) << 16);
    *(uint4*)(AGGb + (size_t)dnode * Cc + sub * 8) = pk;
  }
}

// ---------------- launch ----------------
extern "C" void kernel_launch(void* const* d_in, const int* in_sizes, int n_in,
                              void* d_out, int out_size, void* d_ws, size_t ws_size,
                              hipStream_t stream) {
  const float* user_emb = (const float*)d_in[0];
  const float* movie_emb = (const float*)d_in[1];
  const float* phi = (const float*)d_in[2];
  const float* meta_w = (const float*)d_in[3];
  const float* meta_b = (const float*)d_in[4];
  const float* kw = (const float*)d_in[5];
  const float* kb = (const float*)d_in[6];
  const float* qw = (const float*)d_in[7];
  const float* qb = (const float*)d_in[8];
  const float* vw = (const float*)d_in[9];
  const float* vb = (const float*)d_in[10];
  const float* a_rel = (const float*)d_in[11];
  const float* m_rel = (const float*)d_in[12];
  const float* p_rel = (const float*)d_in[13];
  const float* ow = (const float*)d_in[14];
  const float* ob = (const float*)d_in[15];
  const float* skip = (const float*)d_in[16];
  const int* eidx = (const int*)d_in[17];

  int NU = in_sizes[0] / Cc;
  int NM = in_sizes[1] / Cc;
  int E_ = in_sizes[17] / 2;
  int NT = NU + NM;
  const int* esrc = eidx;
  const int* edst = eidx + E_;

  char* ws = (char*)d_ws;
  size_t off = 0;
  auto alloc = [&](size_t bytes) -> char* {
    char* p = ws + off;
    off = (off + bytes + 255) & ~(size_t)255;
    return p;
  };
  char* Qc = alloc((size_t)NT * 256);
  char* KVc = alloc((size_t)NT * 256);
  unsigned short* Xb = (unsigned short*)alloc((size_t)NT * Cc * 2);
  unsigned short* AGGb = (unsigned short*)alloc((size_t)NT * Cc * 2);
  unsigned short* WT = (unsigned short*)alloc((size_t)Ll * Tt * 384 * Cc * 2);
  unsigned short* OWT = (unsigned short*)alloc((size_t)Ll * Tt * Cc * Cc * 2);
  float* bQKV = (float*)alloc((size_t)Ll * Tt * 384 * 4);
  float* bO = (float*)alloc((size_t)Ll * Tt * Cc * 4);
  int* rowptr = (int*)alloc((size_t)(NT + 1) * 4);
  int* srcAll = (int*)alloc((size_t)2 * E_ * 4);
  int* eoffm = (int*)alloc((size_t)E_ * 4);
  int* eoffu = (int*)alloc((size_t)E_ * 4);
  int* cnt = (int*)alloc((size_t)NT * 4);
  int* cntM32 = (int*)alloc((size_t)32 * NM * 4);
  int* psum = (int*)alloc((size_t)256 * 4);
  float* xout = (float*)d_out;

  int nblk = (NT + 1023) / 1024;
  int PB = 1024;                     // 2048 (g,lt) items / 2 per block
  int IB = (NT * 32 + 255) / 256;    // init: 4 channels per thread
  int HB = (E_ + 2047) / 2048;       // hist: 8 edges per thread

  int NBU = (NU + 127) / 128;
  int NBM = (NM + 127) / 128;
  int GB = NBU + NBM;
  int nagg = (NT + 15) / 16;
  int SB = (E_ + 255) / 256;

  hipMemsetAsync(cnt + NM, 0, (size_t)NU * 4, stream);    // user counters
  hipMemsetAsync(cntM32, 0, (size_t)32 * NM * 4, stream); // movie replicas
  // launch A: histM (32-replica) FIRST | prep | init
  prep_init_kernel<<<HB + PB + IB, 256, 0, stream>>>(
      NM, NU, edst, E_, cntM32, eoffm,
      kw, kb, qw, qb, vw, vb, a_rel, m_rel, p_rel, ow, ob,
      WT, bQKV, OWT, bO,
      user_emb, movie_emb, phi, meta_w, meta_b, xout, Xb, HB, PB);
  // launch B: histU (users) FIRST + QKV l0 GEMM
  mfma_gemm<6, 0><<<HB + GB, 256, 0, stream>>>(
      HB, NBU, NU, NM, (const bf16*)Xb, (const bf16*)WT, bQKV, Qc, KVc,
      nullptr, nullptr, nullptr, esrc, E_, cnt + NM, eoffu);
  colscan32_kernel<<<(NM + 255) / 256, 256, 0, stream>>>(cntM32, cnt, NM);
  scan_p1<<<nblk, 256, 0, stream>>>(cnt, NT, psum);
  scan_p2<<<1, 64, 0, stream>>>(psum, nblk);
  scan_p3<<<nblk, 256, 0, stream>>>(cnt, NT, psum, rowptr);
  scatter_kernel<<<SB, 256, 0, stream>>>(esrc, edst, E_, rowptr, cntM32,
                                         eoffm, eoffu, srcAll, NU, NM);
  // layer 0 (QKV already done)
  agg_kernel<<<nagg, 256, 0, stream>>>(rowptr, srcAll, Qc, KVc, AGGb, NM, NU);
  mfma_gemm<2, 1><<<GB, 256, 0, stream>>>(
      0, NBU, NU, NM, (const bf16*)AGGb, (const bf16*)OWT, bO,
      nullptr, nullptr, xout, Xb, skip, nullptr, 0, nullptr, nullptr);
  // layer 1
  mfma_gemm<6, 0><<<GB, 256, 0, stream>>>(
      0, NBU, NU, NM, (const bf16*)Xb, (const bf16*)(WT + (size_t)2 * 384 * Cc),
      bQKV + (size_t)2 * 384, Qc, KVc, nullptr, nullptr, nullptr,
      nullptr, 0, nullptr, nullptr);
  agg_kernel<<<nagg, 256, 0, stream>>>(rowptr, srcAll, Qc, KVc, AGGb, NM, NU);
  mfma_gemm<2, 1><<<GB, 256, 0, stream>>>(
      0, NBU, NU, NM, (const bf16*)AGGb, (const bf16*)(OWT + (size_t)2 * Cc * Cc),
      bO + (size_t)2 * Cc, nullptr, nullptr, xout, Xb, skip + 2,
      nullptr, 0, nullptr, nullptr);
}

// Round 22
// 263.420 us; speedup vs baseline: 1.0242x; 1.0242x over previous
//
#include <hip/hip_runtime.h>
#include <hip/hip_bf16.h>

#define Cc 128
#define Hh 4
#define Dd 32
#define DPHI2 64
#define Ll 2
#define Tt 2
#define Rr 2

typedef __hip_bfloat16 bf16;
using short8 = __attribute__((ext_vector_type(8))) short;
using f32x4 = __attribute__((ext_vector_type(4))) float;
using f32x2 = __attribute__((ext_vector_type(2))) float;
typedef _Float16 h2 __attribute__((ext_vector_type(2)));
typedef __fp16 fp16x2 __attribute__((ext_vector_type(2)));

__device__ __forceinline__ unsigned short f2bf(float f) {
  union { float f; unsigned u; } v; v.f = f;
  unsigned r = v.u + 0x7fff + ((v.u >> 16) & 1);
  return (unsigned short)(r >> 16);
}
__device__ __forceinline__ h2 u2h(unsigned u) {
  union { unsigned u; h2 h; } v; v.u = u; return v.h;
}
__device__ __forceinline__ unsigned pkh(float a, float b) {
  union { unsigned u; fp16x2 h; } v;
  v.h = __builtin_amdgcn_cvt_pkrtz(a, b);
  return v.u;
}

// ---- fp8 e4m3 helpers (HW cvt on gfx950; guarded fallbacks) ----
__device__ __forceinline__ float fp8_decode1(unsigned char b) {
  unsigned u = b & 0x7f;
  float nrm = __builtin_bit_cast(float, (u << 20) + 0x3C000000u);
  float sub = (float)u * 0.001953125f;
  float v = (u >= 8) ? nrm : sub;
  return (b & 0x80) ? -v : v;
}
template <bool HI>
__device__ __forceinline__ f32x2 fp8x2f(unsigned w) {
#if __has_builtin(__builtin_amdgcn_cvt_pk_f32_fp8)
  return __builtin_amdgcn_cvt_pk_f32_fp8(w, HI);
#else
  unsigned b = HI ? (w >> 16) : (w & 0xffff);
  f32x2 r;
  r[0] = fp8_decode1((unsigned char)b);
  r[1] = fp8_decode1((unsigned char)(b >> 8));
  return r;
#endif
}
#if !__has_builtin(__builtin_amdgcn_cvt_pk_fp8_f32)
__device__ __forceinline__ unsigned char fp8_encode1(float f) {
  unsigned s = (__builtin_bit_cast(unsigned, f) >> 31) << 7;
  float a = fabsf(f);
  a = fminf(a, 448.f);
  unsigned char out;
  if (a < 0.0009765625f) {
    out = 0;
  } else if (a < 0.015625f) {
    out = (unsigned char)(a * 512.f + 0.5f);
  } else {
    unsigned bits = __builtin_bit_cast(unsigned, a);
    int e = (int)(bits >> 23) - 127;
    unsigned m = (bits >> 20) & 7;
    m += (bits >> 19) & 1;
    unsigned ee = (unsigned)(e + 7);
    if (m == 8) { m = 0; ee += 1; }
    if (ee > 15) { ee = 15; m = 6; }
    out = (unsigned char)((ee << 3) | m);
  }
  return out | (unsigned char)s;
}
#endif
__device__ __forceinline__ unsigned pk_fp8x4(float v0, float v1, float v2, float v3) {
#if __has_builtin(__builtin_amdgcn_cvt_pk_fp8_f32)
  int p = __builtin_amdgcn_cvt_pk_fp8_f32(v0, v1, 0, false);
  p = __builtin_amdgcn_cvt_pk_fp8_f32(v2, v3, p, true);
  return (unsigned)p;
#else
  return (unsigned)fp8_encode1(v0) | ((unsigned)fp8_encode1(v1) << 8) |
         ((unsigned)fp8_encode1(v2) << 16) | ((unsigned)fp8_encode1(v3) << 24);
#endif
}

// ---- DPP quad reduce (xor1, xor2 within each 4-lane quad) ----
__device__ __forceinline__ float dpp_add_xor1(float x) {
  int v = __builtin_amdgcn_update_dpp(0, __builtin_bit_cast(int, x), 0xB1, 0xF, 0xF, true);
  return x + __builtin_bit_cast(float, v);
}
__device__ __forceinline__ float dpp_add_xor2(float x) {
  int v = __builtin_amdgcn_update_dpp(0, __builtin_bit_cast(int, x), 0x4E, 0xF, 0xF, true);
  return x + __builtin_bit_cast(float, v);
}

__device__ __forceinline__ float gelu_tanh(float x) {
  float u = 0.7978845608028654f * (x + 0.044715f * x * x * x);
  float t = 1.f - 2.f / (__expf(2.f * u) + 1.f);  // tanh(u)
  return 0.5f * x * (1.f + t);
}

// async 16B global->LDS (LDS dest = wave-uniform base + lane*16)
__device__ __forceinline__ void gload_lds16(const void* gsrc, void* lds) {
  __builtin_amdgcn_global_load_lds(
      (const __attribute__((address_space(1))) unsigned int*)gsrc,
      (__attribute__((address_space(3))) unsigned int*)lds, 16, 0, 0);
}

// ---------------- histM(8-replica) | prep | init --------------------------------
// blocks [0,HBm): movie-side hist, 8 edges/thread; replica r=(e>>13)&7:
//   eoffm[e] = atomicAdd(&cntM8[r*NM+d], 1)  -> per-address contention /8
// blocks [HBm,HBm+PB): prep; blocks [HBm+PB,...): init xout/Xb (float4)
__global__ __launch_bounds__(256) void prep_init_kernel(
    int NM_, int NU_,
    const int* __restrict__ edst, int E_, int* __restrict__ cntM8,
    int* __restrict__ eoffm,
    const float* __restrict__ kw, const float* __restrict__ kb,
    const float* __restrict__ qw, const float* __restrict__ qb,
    const float* __restrict__ vw, const float* __restrict__ vb,
    const float* __restrict__ a_rel, const float* __restrict__ m_rel,
    const float* __restrict__ p_rel, const float* __restrict__ ow,
    const float* __restrict__ ob,
    unsigned short* __restrict__ WT, float* __restrict__ bQKV,
    unsigned short* __restrict__ OWT, float* __restrict__ bO,
    const float* __restrict__ ue, const float* __restrict__ me,
    const float* __restrict__ phi, const float* __restrict__ mw,
    const float* __restrict__ mb,
    float* __restrict__ xout, unsigned short* __restrict__ Xb,
    int HBm, int PB) {
  int b = blockIdx.x;
  if (b < HBm) {
    int base_e = b * 2048;
#pragma unroll
    for (int j = 0; j < 8; ++j) {
      int e = base_e + j * 256 + (int)threadIdx.x;
      if (e < E_) {
        int rep = (e >> 13) & 7;
        eoffm[e] = atomicAdd(&cntM8[rep * NM_ + edst[e]], 1);
      }
    }
    return;
  }
  b -= HBm;
  if (b < PB) {
    int idx = b * 2 + (threadIdx.x >> 7);  // (g,lt) item, 2048 total
    int g = idx >> 2, lt = idx & 3;
    int l = lt >> 1, t = lt & 1, r = t;
    int k = threadIdx.x & 127;
    const float inv_sqrt_d = 0.17677669529663687f;
    const float QSCALE = 1.4426950408889634f / 256.f;  // log2e / S_k
    float val, bval;
    if (g < 128) {
      val = qw[((size_t)lt * Cc + k) * Cc + g] * QSCALE;
      bval = qb[(size_t)lt * Cc + g] * QSCALE;
    } else if (g < 384) {
      int isV = (g >= 256);
      int n = g - (isV ? 256 : 128);
      int h = n >> 5, e = n & 31;
      const float* W = (isV ? vw : kw) + (size_t)lt * Cc * Cc;
      const float* bb = (isV ? vb : kb) + (size_t)lt * Cc;
      const float* Ah = (isV ? m_rel : a_rel) + (((size_t)l * Rr + r) * Hh + h) * Dd * Dd;
      float s = 0.f, sb = 0.f;
      for (int d = 0; d < Dd; ++d) {
        float ae = Ah[d * Dd + e];
        s += W[(size_t)k * Cc + h * Dd + d] * ae;
        sb += bb[h * Dd + d] * ae;
      }
      float scale = isV ? 256.f : p_rel[((size_t)l * Rr + r) * Hh + h] * inv_sqrt_d * 256.f;
      val = s * scale;
      bval = sb * scale;
    } else {
      int n = g - 384;
      val = ow[((size_t)lt * Cc + k) * Cc + n];
      bval = ob[(size_t)lt * Cc + n];
    }
    if (g < 384) {
      WT[((size_t)lt * 384 + g) * Cc + k] = f2bf(val);
      if (k == 0) bQKV[(size_t)lt * 384 + g] = bval;
    } else {
      OWT[((size_t)lt * Cc + (g - 384)) * Cc + k] = f2bf(val);
      if (k == 0) bO[(size_t)lt * Cc + (g - 384)] = bval;
    }
    return;
  }
  // init: 4 channels per thread
  int i4 = (b - PB) * 256 + threadIdx.x;          // group index (4 ch/group)
  int totalU4 = NU_ * 32;                          // 128/4 groups per row
  float4 s;
  size_t o;
  if (i4 < totalU4) {
    o = (size_t)i4 * 4;
    s = *(const float4*)&ue[o];
  } else {
    int mg = i4 - totalU4;
    if (mg >= NM_ * 32) return;
    int m = mg >> 5, c = (mg & 31) * 4;
    o = (size_t)(NU_ * 32 + mg) * 4;
    s = *(const float4*)&me[(size_t)m * Cc + c];
    float4 bmv = *(const float4*)&mb[c];
    s.x += bmv.x; s.y += bmv.y; s.z += bmv.z; s.w += bmv.w;
    const float* ph = phi + (size_t)m * DPHI2;
#pragma unroll 4
    for (int d = 0; d < DPHI2; ++d) {
      float p = ph[d];
      float4 w4 = *(const float4*)&mw[d * Cc + c];
      s.x += p * w4.x; s.y += p * w4.y; s.z += p * w4.z; s.w += p * w4.w;
    }
  }
  *(float4*)&xout[o] = s;
  uint2 pk;
  pk.x = (unsigned)f2bf(s.x) | ((unsigned)f2bf(s.y) << 16);
  pk.y = (unsigned)f2bf(s.z) | ((unsigned)f2bf(s.w) << 16);
  *(uint2*)&Xb[o] = pk;
}

// ---------------- colscan8: cntM8[r][d] -> per-replica bases + movie totals ----
__global__ __launch_bounds__(256) void colscan8_kernel(int* __restrict__ cntM8,
                                                       int* __restrict__ cnt, int NM_) {
  int d = blockIdx.x * 256 + threadIdx.x;
  if (d >= NM_) return;
  int run = 0;
#pragma unroll
  for (int r = 0; r < 8; ++r) {
    int* p = cntM8 + (size_t)r * NM_ + d;
    int t = *p;
    *p = run;
    run += t;
  }
  cnt[d] = run;
}

// 3-phase parallel scan: 1024 elems per block
__global__ __launch_bounds__(256) void scan_p1(const int* __restrict__ cnt, int n,
                                               int* __restrict__ psum) {
  int i0 = blockIdx.x * 1024 + threadIdx.x * 4;
  int s = 0;
#pragma unroll
  for (int j = 0; j < 4; ++j) {
    int i = i0 + j;
    if (i < n) s += cnt[i];
  }
#pragma unroll
  for (int off = 1; off < 64; off <<= 1) s += __shfl_xor(s, off, 64);
  __shared__ int wsum[4];
  if ((threadIdx.x & 63) == 0) wsum[threadIdx.x >> 6] = s;
  __syncthreads();
  if (threadIdx.x == 0) psum[blockIdx.x] = wsum[0] + wsum[1] + wsum[2] + wsum[3];
}
__global__ void scan_p2(int* psum, int nb) {
  if (threadIdx.x == 0 && blockIdx.x == 0) {
    int run = 0;
    for (int i = 0; i < nb; ++i) { int v = psum[i]; psum[i] = run; run += v; }
  }
}
__global__ __launch_bounds__(256) void scan_p3(const int* __restrict__ cnt, int n,
                                               const int* __restrict__ psum,
                                               int* __restrict__ rowptr) {
  __shared__ int sdata[256];
  int i0 = blockIdx.x * 1024 + threadIdx.x * 4;
  int a0 = (i0 + 0 < n) ? cnt[i0 + 0] : 0;
  int a1 = (i0 + 1 < n) ? cnt[i0 + 1] : 0;
  int a2 = (i0 + 2 < n) ? cnt[i0 + 2] : 0;
  int a3 = (i0 + 3 < n) ? cnt[i0 + 3] : 0;
  int s = a0 + a1 + a2 + a3;
  sdata[threadIdx.x] = s;
  __syncthreads();
  for (int off = 1; off < 256; off <<= 1) {
    int t = ((int)threadIdx.x >= off) ? sdata[threadIdx.x - off] : 0;
    __syncthreads();
    sdata[threadIdx.x] += t;
    __syncthreads();
  }
  int run = psum[blockIdx.x] + sdata[threadIdx.x] - s;
  if (i0 + 0 < n) rowptr[i0 + 1] = run + a0;
  if (i0 + 1 < n) rowptr[i0 + 2] = run + a0 + a1;
  if (i0 + 2 < n) rowptr[i0 + 3] = run + a0 + a1 + a2;
  if (i0 + 3 < n) rowptr[i0 + 4] = run + s;
  if (blockIdx.x == 0 && threadIdx.x == 0) rowptr[0] = 0;
}

// ---------------- standalone scatter (atomic-free; movie base via cntM8) -------
__global__ void scatter_kernel(const int* __restrict__ esrc, const int* __restrict__ edst,
                               int E_, const int* __restrict__ rowptr,
                               const int* __restrict__ cntM8,
                               const int* __restrict__ eoffm, const int* __restrict__ eoffu,
                               int* __restrict__ srcAll, int NU_, int NM_) {
  int e = blockIdx.x * 256 + threadIdx.x;
  if (e < E_) {
    int s = esrc[e], d = edst[e];
    int rep = (e >> 13) & 7;
    int mbase = cntM8[(size_t)rep * NM_ + d];
    srcAll[rowptr[d] + mbase + eoffm[e]] = s << 8;
    srcAll[rowptr[NM_ + s] + eoffu[e]] = (NU_ + d) << 8;
  }
}

// ---------------- MFMA GEMM (LDS double-buffered B) + prepended HIST-U blocks --
// MODE 0 blocks [0,HB): user-side hist (8 edges/thread): eoffu[e]=atomicAdd(cntU,1)
// blocks [HB, HB+GB): GEMM (users then movies, 128 rows/block).
// MODE 0: QKV proj -> Qc f16 (256B rows) + KVc fp8 rows (256B, [K8|V8]/octet).
// MODE 1: out proj + skip-mix -> xout (f32) + Xb (bf16)  (HB==0)
template <int NCH, int MODE>
__global__ __launch_bounds__(256, 2) void mfma_gemm(
    int HB, int NBU_, int NU_, int NM_,
    const bf16* __restrict__ Abase,
    const bf16* __restrict__ WTl, const float* __restrict__ biasl,
    char* __restrict__ Qc, char* __restrict__ KVc,
    float* __restrict__ xout, unsigned short* __restrict__ Xb,
    const float* __restrict__ skipl,
    const int* __restrict__ esrc, int E_,
    int* __restrict__ cntU, int* __restrict__ eoffu) {
  __shared__ char Bs[2][16384];
  if (MODE == 0 && (int)blockIdx.x < HB) {  // ---- hist-U blocks ----
    int base_e = (int)blockIdx.x * 2048;
#pragma unroll
    for (int j = 0; j < 8; ++j) {
      int e = base_e + j * 256 + (int)threadIdx.x;
      if (e < E_) eoffu[e] = atomicAdd(&cntU[esrc[e]], 1);
    }
    return;
  }
  int bx = (int)blockIdx.x - ((MODE == 0) ? HB : 0);
  int t, row0, M, base;
  if (bx < NBU_) { t = 0; row0 = bx * 128; M = NU_; base = 0; }
  else { t = 1; row0 = (bx - NBU_) * 128; M = NM_; base = NU_; }
  const char* BT = (const char*)(WTl + (size_t)t * (NCH * 64) * Cc);
  const float* bias = biasl + (size_t)t * (NCH * 64);
  int wid = threadIdx.x >> 6, lane = threadIdx.x & 63;
  int rw = row0 + wid * 32;
  bool wact = rw < M;                    // no early return: barriers below
  int lr = lane & 15, lk8 = (lane >> 4) * 8;

  auto stage = [&](int ch, int buf) {
    const char* src = BT + (size_t)ch * 16384;
#pragma unroll
    for (int j = 0; j < 4; ++j) {
      int u = wid * 4 + j;
      int d = u * 1024 + lane * 16;                 // linear LDS dest byte
      int g = d ^ (((d >> 8) & 7) << 4);            // pre-swizzled global src
      gload_lds16(src + g, &Bs[buf][u * 1024]);
    }
  };

  short8 a[2][4];
#pragma unroll
  for (int mt = 0; mt < 2; ++mt) {
    int r = rw + mt * 16 + lr;
    const bf16* ap = Abase + (size_t)(base + r) * Cc + lk8;
#pragma unroll
    for (int kk = 0; kk < 4; ++kk) {
      short8 v = {};
      if (wact && r < M) v = *(const short8*)(ap + kk * 32);
      a[mt][kk] = v;
    }
  }
  float g = 0.f;
  if (MODE == 1) g = 1.f / (1.f + __expf(-skipl[t]));

  stage(0, 0);
#pragma unroll
  for (int ch = 0; ch < NCH; ++ch) {
    int buf = ch & 1;
    __syncthreads();                 // drains vmcnt -> chunk ch arrived
    if (ch + 1 < NCH) stage(ch + 1, buf ^ 1);
    short8 b[4][4];
#pragma unroll
    for (int nt = 0; nt < 4; ++nt) {
      int r = nt * 16 + lr;
#pragma unroll
      for (int kk = 0; kk < 4; ++kk) {
        int a0 = r * 256 + (lk8 + kk * 32) * 2;
        b[nt][kk] = *(const short8*)(&Bs[buf][a0 ^ ((r & 7) << 4)]);
      }
    }
    f32x4 acc[2][4];
#pragma unroll
    for (int mt = 0; mt < 2; ++mt)
#pragma unroll
      for (int nt = 0; nt < 4; ++nt) acc[mt][nt] = (f32x4){0.f, 0.f, 0.f, 0.f};
#pragma unroll
    for (int kk = 0; kk < 4; ++kk)
#pragma unroll
      for (int mt = 0; mt < 2; ++mt)
#pragma unroll
        for (int nt = 0; nt < 4; ++nt)
          acc[mt][nt] = __builtin_amdgcn_mfma_f32_16x16x32_bf16(
              b[nt][kk], a[mt][kk], acc[mt][nt], 0, 0, 0);  // C^T: lane = 1 row, 4 cols
    if (!wact) continue;
#pragma unroll
    for (int mt = 0; mt < 2; ++mt) {
      int r = rw + mt * 16 + lr;
      if (r >= M) continue;
      size_t grow = (size_t)(base + r);
#pragma unroll
      for (int nt = 0; nt < 4; ++nt) {
        int cb = ch * 64 + nt * 16 + 4 * (lane >> 4);
        float4 b4 = *(const float4*)&bias[cb];
        float v0 = acc[mt][nt][0] + b4.x;
        float v1 = acc[mt][nt][1] + b4.y;
        float v2 = acc[mt][nt][2] + b4.z;
        float v3 = acc[mt][nt][3] + b4.w;
        if (MODE == 0) {
          if (cb < Cc) {
            uint2 pk;
            pk.x = pkh(v0, v1); pk.y = pkh(v2, v3);
            *(uint2*)(Qc + grow * 256 + cb * 2) = pk;
          } else {
            int c = cb - 128;          // 0..255: [0,128)=K, [128,256)=V
            int isv = c >> 7; c &= 127;
            int off = (c >> 3) * 16 + (c & 7) + isv * 8;
            unsigned pk = pk_fp8x4(v0, v1, v2, v3);
            *(unsigned*)(KVc + grow * 256 + off) = pk;
          }
        } else {
          float* xp = xout + grow * Cc + cb;
          float4 old = *(const float4*)xp;
          float n0 = g * v0 + (1.f - g) * old.x;
          float n1 = g * v1 + (1.f - g) * old.y;
          float n2 = g * v2 + (1.f - g) * old.z;
          float n3 = g * v3 + (1.f - g) * old.w;
          *(float4*)xp = make_float4(n0, n1, n2, n3);
          uint2 pk;
          pk.x = (unsigned)f2bf(n0) | ((unsigned)f2bf(n1) << 16);
          pk.y = (unsigned)f2bf(n2) | ((unsigned)f2bf(n3) << 16);
          *(uint2*)(Xb + grow * Cc + cb) = pk;
        }
      }
    }
  }
}

// ---------------- fused softmax+agg: SLOT-PER-DST, 4-edge ILP -------------------
__global__ __launch_bounds__(256) void agg_kernel(
    const int* __restrict__ rowptr, const int* __restrict__ srcAll,
    const char* __restrict__ Qc, const char* __restrict__ KVc,
    unsigned short* __restrict__ AGGb, int NM_, int NU_) {
  int wid = threadIdx.x >> 6, lane = threadIdx.x & 63;
  int sub = lane & 15, eo = lane >> 4;
  int NT_ = NM_ + NU_;
  int W = (blockIdx.x * 4 + wid) * 4 + eo;   // this slot's dst
  bool active = W < NT_;
  int Wc = active ? W : NT_ - 1;
  int beg = rowptr[Wc];
  int end = active ? rowptr[Wc + 1] : beg;
  int dnode = (Wc < NM_) ? (NU_ + Wc) : (Wc - NM_);
  int myoff = sub * 16;
  uint4 qv = *(const uint4*)(Qc + (size_t)dnode * 256 + myoff);
  float qf0, qf1, qf2, qf3, qf4, qf5, qf6, qf7;
  {
    h2 t0 = u2h(qv.x), t1 = u2h(qv.y), t2 = u2h(qv.z), t3 = u2h(qv.w);
    qf0 = (float)t0[0]; qf1 = (float)t0[1];
    qf2 = (float)t1[0]; qf3 = (float)t1[1];
    qf4 = (float)t2[0]; qf5 = (float)t2[1];
    qf6 = (float)t3[0]; qf7 = (float)t3[1];
  }
  float acc0 = 0.f, acc1 = 0.f, acc2 = 0.f, acc3 = 0.f;
  float acc4 = 0.f, acc5 = 0.f, acc6 = 0.f, acc7 = 0.f;
  float denom = 0.f;
  const char* KVp = KVc + myoff;

#define CONSUME(KV, WVALID)                                                       \
  {                                                                               \
    f32x2 k01 = fp8x2f<false>((KV).x), k23 = fp8x2f<true>((KV).x);                \
    f32x2 k45 = fp8x2f<false>((KV).y), k67 = fp8x2f<true>((KV).y);                \
    float pA = qf0 * k01[0] + qf1 * k01[1] + qf2 * k23[0] + qf3 * k23[1];         \
    float pB = qf4 * k45[0] + qf5 * k45[1] + qf6 * k67[0] + qf7 * k67[1];         \
    float p = pA + pB;                                                            \
    p = dpp_add_xor1(p);                                                          \
    p = dpp_add_xor2(p);                                                          \
    float w = (WVALID) ? exp2f(p) : 0.f;                                          \
    denom += w;                                                                   \
    f32x2 v01 = fp8x2f<false>((KV).z), v23 = fp8x2f<true>((KV).z);                \
    f32x2 v45 = fp8x2f<false>((KV).w), v67 = fp8x2f<true>((KV).w);                \
    acc0 += w * v01[0]; acc1 += w * v01[1];                                       \
    acc2 += w * v23[0]; acc3 += w * v23[1];                                       \
    acc4 += w * v45[0]; acc5 += w * v45[1];                                       \
    acc6 += w * v67[0]; acc7 += w * v67[1];                                       \
  }

  for (int e = beg; __any(e < end); e += 4) {
    bool v0 = e < end, v1 = (e + 1) < end, v2 = (e + 2) < end, v3 = (e + 3) < end;
    int so0 = srcAll[v0 ? e : 0];
    int so1 = srcAll[v1 ? (e + 1) : 0];
    int so2 = srcAll[v2 ? (e + 2) : 0];
    int so3 = srcAll[v3 ? (e + 3) : 0];
    uint4 kv0 = *(const uint4*)(KVp + (size_t)(unsigned)so0);
    uint4 kv1 = *(const uint4*)(KVp + (size_t)(unsigned)so1);
    uint4 kv2 = *(const uint4*)(KVp + (size_t)(unsigned)so2);
    uint4 kv3 = *(const uint4*)(KVp + (size_t)(unsigned)so3);
    CONSUME(kv0, v0)
    CONSUME(kv1, v1)
    CONSUME(kv2, v2)
    CONSUME(kv3, v3)
  }
#undef CONSUME

  if (active) {
    float inv = 1.f / (denom + 1e-16f) * 0.00390625f;  // /256 V scale
    float o0 = gelu_tanh(acc0 * inv);
    float o1 = gelu_tanh(acc1 * inv);
    float o2 = gelu_tanh(acc2 * inv);
    float o3 = gelu_tanh(acc3 * inv);
    float o4 = gelu_tanh(acc4 * inv);
    float o5 = gelu_tanh(acc5 * inv);
    float o6 = gelu_tanh(acc6 * inv);
    float o7 = gelu_tanh(acc7 * inv);
    uint4 pk;
    pk.x = (unsigned)f2bf(o0) | ((unsigned)f2bf(o1) << 16);
    pk.y = (unsigned)f2bf(o2) | ((unsigned)f2bf(o3) << 16);
    pk.z = (unsigned)f2bf(o4) | ((unsigned)f2bf(o5) << 16);
    pk.w = (unsigned)f2bf(o6) | ((unsigned)f2bf(o7) << 16);
    *(uint4*)(AGGb + (size_t)dnode * Cc + sub * 8) = pk;
  }
}

// ---------------- launch ----------------
extern "C" void kernel_launch(void* const* d_in, const int* in_sizes, int n_in,
                              void* d_out, int out_size, void* d_ws, size_t ws_size,
                              hipStream_t stream) {
  const float* user_emb = (const float*)d_in[0];
  const float* movie_emb = (const float*)d_in[1];
  const float* phi = (const float*)d_in[2];
  const float* meta_w = (const float*)d_in[3];
  const float* meta_b = (const float*)d_in[4];
  const float* kw = (const float*)d_in[5];
  const float* kb = (const float*)d_in[6];
  const float* qw = (const float*)d_in[7];
  const float* qb = (const float*)d_in[8];
  const float* vw = (const float*)d_in[9];
  const float* vb = (const float*)d_in[10];
  const float* a_rel = (const float*)d_in[11];
  const float* m_rel = (const float*)d_in[12];
  const float* p_rel = (const float*)d_in[13];
  const float* ow = (const float*)d_in[14];
  const float* ob = (const float*)d_in[15];
  const float* skip = (const float*)d_in[16];
  const int* eidx = (const int*)d_in[17];

  int NU = in_sizes[0] / Cc;
  int NM = in_sizes[1] / Cc;
  int E_ = in_sizes[17] / 2;
  int NT = NU + NM;
  const int* esrc = eidx;
  const int* edst = eidx + E_;

  char* ws = (char*)d_ws;
  size_t off = 0;
  auto alloc = [&](size_t bytes) -> char* {
    char* p = ws + off;
    off = (off + bytes + 255) & ~(size_t)255;
    return p;
  };
  char* Qc = alloc((size_t)NT * 256);
  char* KVc = alloc((size_t)NT * 256);
  unsigned short* Xb = (unsigned short*)alloc((size_t)NT * Cc * 2);
  unsigned short* AGGb = (unsigned short*)alloc((size_t)NT * Cc * 2);
  unsigned short* WT = (unsigned short*)alloc((size_t)Ll * Tt * 384 * Cc * 2);
  unsigned short* OWT = (unsigned short*)alloc((size_t)Ll * Tt * Cc * Cc * 2);
  float* bQKV = (float*)alloc((size_t)Ll * Tt * 384 * 4);
  float* bO = (float*)alloc((size_t)Ll * Tt * Cc * 4);
  int* rowptr = (int*)alloc((size_t)(NT + 1) * 4);
  int* srcAll = (int*)alloc((size_t)2 * E_ * 4);
  int* eoffm = (int*)alloc((size_t)E_ * 4);
  int* eoffu = (int*)alloc((size_t)E_ * 4);
  int* cnt = (int*)alloc((size_t)NT * 4);
  int* cntM8 = (int*)alloc((size_t)8 * NM * 4);
  int* psum = (int*)alloc((size_t)256 * 4);
  float* xout = (float*)d_out;

  int nblk = (NT + 1023) / 1024;
  int PB = 1024;                     // 2048 (g,lt) items / 2 per block
  int IB = (NT * 32 + 255) / 256;    // init: 4 channels per thread
  int HB = (E_ + 2047) / 2048;       // hist: 8 edges per thread

  int NBU = (NU + 127) / 128;
  int NBM = (NM + 127) / 128;
  int GB = NBU + NBM;
  int nagg = (NT + 15) / 16;
  int SB = (E_ + 255) / 256;

  hipMemsetAsync(cnt + NM, 0, (size_t)NU * 4, stream);   // user counters
  hipMemsetAsync(cntM8, 0, (size_t)8 * NM * 4, stream);  // movie replicas
  // launch A: histM (8-replica) FIRST | prep | init
  prep_init_kernel<<<HB + PB + IB, 256, 0, stream>>>(
      NM, NU, edst, E_, cntM8, eoffm,
      kw, kb, qw, qb, vw, vb, a_rel, m_rel, p_rel, ow, ob,
      WT, bQKV, OWT, bO,
      user_emb, movie_emb, phi, meta_w, meta_b, xout, Xb, HB, PB);
  // launch B: histU (users) FIRST + QKV l0 GEMM
  mfma_gemm<6, 0><<<HB + GB, 256, 0, stream>>>(
      HB, NBU, NU, NM, (const bf16*)Xb, (const bf16*)WT, bQKV, Qc, KVc,
      nullptr, nullptr, nullptr, esrc, E_, cnt + NM, eoffu);
  colscan8_kernel<<<(NM + 255) / 256, 256, 0, stream>>>(cntM8, cnt, NM);
  scan_p1<<<nblk, 256, 0, stream>>>(cnt, NT, psum);
  scan_p2<<<1, 64, 0, stream>>>(psum, nblk);
  scan_p3<<<nblk, 256, 0, stream>>>(cnt, NT, psum, rowptr);
  scatter_kernel<<<SB, 256, 0, stream>>>(esrc, edst, E_, rowptr, cntM8,
                                         eoffm, eoffu, srcAll, NU, NM);
  // layer 0 (QKV already done)
  agg_kernel<<<nagg, 256, 0, stream>>>(rowptr, srcAll, Qc, KVc, AGGb, NM, NU);
  mfma_gemm<2, 1><<<GB, 256, 0, stream>>>(
      0, NBU, NU, NM, (const bf16*)AGGb, (const bf16*)OWT, bO,
      nullptr, nullptr, xout, Xb, skip, nullptr, 0, nullptr, nullptr);
  // layer 1
  mfma_gemm<6, 0><<<GB, 256, 0, stream>>>(
      0, NBU, NU, NM, (const bf16*)Xb, (const bf16*)(WT + (size_t)2 * 384 * Cc),
      bQKV + (size_t)2 * 384, Qc, KVc, nullptr, nullptr, nullptr,
      nullptr, 0, nullptr, nullptr);
  agg_kernel<<<nagg, 256, 0, stream>>>(rowptr, srcAll, Qc, KVc, AGGb, NM, NU);
  mfma_gemm<2, 1><<<GB, 256, 0, stream>>>(
      0, NBU, NU, NM, (const bf16*)AGGb, (const bf16*)(OWT + (size_t)2 * Cc * Cc),
      bO + (size_t)2 * Cc, nullptr, nullptr, xout, Xb, skip + 2,
      nullptr, 0, nullptr, nullptr);
}